// Round 10
// baseline (308.641 us; speedup 1.0000x reference)
//
#include <hip/hip_runtime.h>
#include <hip/hip_bf16.h>
#include <math.h>

#define TLEN 1024
#define HDIM 2048
#define NHEAD 32
#define HSZ 64
#define THE (TLEN * HDIM)
#define NC 32          // scan chunks
#define CT (TLEN / NC) // 32 timesteps per chunk

typedef __attribute__((ext_vector_type(8))) short bf16x8;
typedef __attribute__((ext_vector_type(4))) float f32x4;

__device__ __forceinline__ float waveRedSum(float v) {
#pragma unroll
  for (int off = 32; off > 0; off >>= 1) v += __shfl_xor(v, off, 64);
  return v;
}

__device__ __forceinline__ void gll16(const __hip_bfloat16* g, __hip_bfloat16* l) {
  __builtin_amdgcn_global_load_lds(
      (const __attribute__((address_space(1))) void*)g,
      (__attribute__((address_space(3))) void*)l, 16, 0, 0);
}

// ---------- weight convert + transpose: src f32 [R][C] -> dst bf16 [C][R] ----------
struct TrArgs {
  const float* src[8];
  __hip_bfloat16* dst[8];
  int R[8];
  int C[8];
};

__global__ __launch_bounds__(256) void transp_kernel(TrArgs ta) {
  const int z = blockIdx.z;
  const int R = ta.R[z], C = ta.C[z];
  const int c0 = blockIdx.x * 32, r0 = blockIdx.y * 32;
  if (c0 >= C || r0 >= R) return;
  __shared__ float tile[32][33];
  const int tx = threadIdx.x & 31, ty = threadIdx.x >> 5;
  const float* src = ta.src[z];
  __hip_bfloat16* dst = ta.dst[z];
#pragma unroll
  for (int i = 0; i < 4; i++)
    tile[ty + i * 8][tx] = src[(size_t)(r0 + ty + i * 8) * C + c0 + tx];
  __syncthreads();
#pragma unroll
  for (int i = 0; i < 4; i++)
    dst[(size_t)(c0 + ty + i * 8) * R + r0 + tx] = __float2bfloat16(tile[tx][ty + i * 8]);
}

// ---------- LayerNorm (row) + state1_out ----------
__global__ __launch_bounds__(256) void ln1_kernel(const float* __restrict__ x,
                                                  const float* __restrict__ w,
                                                  const float* __restrict__ b,
                                                  float* __restrict__ xl,
                                                  float* __restrict__ s1out) {
  const int t = blockIdx.x;
  const int tid = threadIdx.x;
  const int wid = tid >> 6, lane = tid & 63;
  const float4* xr = (const float4*)(x + (size_t)t * HDIM);
  float4 a = xr[tid];
  float4 c = xr[tid + 256];
  float va[8] = {a.x, a.y, a.z, a.w, c.x, c.y, c.z, c.w};
  float sum = 0.f;
#pragma unroll
  for (int i = 0; i < 8; i++) sum += va[i];
  sum = waveRedSum(sum);
  __shared__ float red[8];
  if (lane == 0) red[wid] = sum;
  __syncthreads();
  const float mu = (red[0] + red[1] + red[2] + red[3]) * (1.f / HDIM);
  float vs = 0.f;
#pragma unroll
  for (int i = 0; i < 8; i++) { float d = va[i] - mu; vs += d * d; }
  vs = waveRedSum(vs);
  if (lane == 0) red[4 + wid] = vs;
  __syncthreads();
  const float rstd = rsqrtf((red[4] + red[5] + red[6] + red[7]) * (1.f / HDIM) + 1e-5f);
  float* xrow = xl + (size_t)t * HDIM;
#pragma unroll
  for (int i = 0; i < 8; i++) {
    const int idx = (i < 4) ? (4 * tid + i) : (1024 + 4 * tid + (i - 4));
    const float o = (va[i] - mu) * rstd * w[idx] + b[idx];
    xrow[idx] = o;
    if (t == TLEN - 1) s1out[idx] = o;
  }
}

// ---------- token shift: xxx = xl + (past - xl) * time_maa_x ----------
__global__ __launch_bounds__(256) void tokshift_kernel(const float* __restrict__ xl,
                                                       const float* __restrict__ s1,
                                                       const float* __restrict__ tmx,
                                                       __hip_bfloat16* __restrict__ xxx) {
  const int t = blockIdx.x;
  const int h = blockIdx.y * 256 + threadIdx.x;
  const float cur = xl[(size_t)t * HDIM + h];
  const float past = (t > 0) ? xl[(size_t)(t - 1) * HDIM + h] : s1[h];
  xxx[(size_t)t * HDIM + h] = __float2bfloat16(cur + (past - cur) * tmx[h]);
}

// ---------- mix: x5[f] = xl + sx * (t5[f] @ w2[f] + time_maa[f]) ----------
__global__ __launch_bounds__(256) void mix_kernel(const float* __restrict__ t5,
                                                  const float* __restrict__ xl,
                                                  const float* __restrict__ s1,
                                                  const float* __restrict__ w2,
                                                  const float* __restrict__ maa,
                                                  __hip_bfloat16* __restrict__ x5b) {
  const int h = blockIdx.x * 256 + threadIdx.x;
  const int t0 = blockIdx.y * 8;
  __shared__ float t5L[8 * 160];
  for (int i = threadIdx.x; i < 8 * 160; i += 256) {
    const int rr = i / 160, cc = i - rr * 160;
    t5L[i] = t5[(size_t)(t0 + rr) * 160 + cc];
  }
  __syncthreads();
  float mixv[8][5];
#pragma unroll
  for (int ts = 0; ts < 8; ts++)
#pragma unroll
    for (int f = 0; f < 5; f++) mixv[ts][f] = 0.f;
#pragma unroll
  for (int f = 0; f < 5; f++) {
#pragma unroll 4
    for (int m = 0; m < 32; m++) {
      const float w2v = w2[(size_t)(f * 32 + m) * HDIM + h];
#pragma unroll
      for (int ts = 0; ts < 8; ts++) mixv[ts][f] += t5L[ts * 160 + f * 32 + m] * w2v;
    }
  }
#pragma unroll
  for (int ts = 0; ts < 8; ts++) {
    const int t = t0 + ts;
    const float cur = xl[(size_t)t * HDIM + h];
    const float past = (t > 0) ? xl[(size_t)(t - 1) * HDIM + h] : s1[h];
    const float sx = past - cur;
#pragma unroll
    for (int f = 0; f < 5; f++) {
      const float v = cur + sx * (mixv[ts][f] + maa[(size_t)f * HDIM + h]);
      x5b[(size_t)f * THE + (size_t)t * HDIM + h] = __float2bfloat16(v);
    }
  }
}

// ---------- batched MFMA GEMM: C[z] = epi( A[z](MxK) @ Bt[z](NxK)^T ) ----------
// BK=64, double-buffered LDS, counted-vmcnt pipeline (prefetch stays in flight
// across barriers), bank-conflict-free XOR swizzle. [round-8 proven structure]
// K = loop length (may be a split-K slice); Ks = row stride of A and Bt.
// epi: 0=bf16, 1=bf16 silu, 2=f32 tanh, 3=bf16 tanh, 4=f32 td, 5=f32 +residual, 6=f32 raw partial
struct GemmArgs {
  const __hip_bfloat16* A[8];
  const __hip_bfloat16* B[8];
  void* C[8];
  const float* aux[8];
  int epi[8];
  int M, N, K, Ks;
};

__global__ __launch_bounds__(256) void gemm_bt(GemmArgs ga) {
  const int z = blockIdx.z;
  const __hip_bfloat16* __restrict__ A = ga.A[z];
  const __hip_bfloat16* __restrict__ Bt = ga.B[z];
  const int N = ga.N, K = ga.K, Ks = ga.Ks;
  const int epi = ga.epi[z];
  const float* __restrict__ aux = ga.aux[z];
  void* Cz = ga.C[z];

  // [2 buffers][128 rows][64 cols] bf16 (128B rows)
  __shared__ __align__(16) __hip_bfloat16 As[2][128 * 64];
  __shared__ __align__(16) __hip_bfloat16 Bs[2][128 * 64];

  const int tid = threadIdx.x;
  const int wid = tid >> 6;
  const int lane = tid & 63;

  // XCD-aware swizzle for the 8x16 grids: cluster all 8 m-blocks of one
  // n-panel onto a single XCD so the B panel stays L2-resident.
  int bx = blockIdx.x, by = blockIdx.y;
  if (gridDim.x == 8 && gridDim.y == 16) {
    const int flat = bx + 8 * by;  // 0..127
    const int xcd = flat & 7, rem = flat >> 3;
    bx = rem & 7;
    by = xcd + 8 * (rem >> 3);
  }
  const int m0 = bx * 128;
  const int n0 = by * 128;
  const int wr = wid >> 1, wc = wid & 1;

  // Staging: call q (per wave) covers rows wid*32+q*8 .. +7.
  // lane l -> row +(l>>3), LDS slot l&7 (16B slots in a 128B row).
  // Pre-swizzled source: phys slot p of row r holds global chunk p ^ (r&7).
  const int srow = lane >> 3;              // 0..7
  const int chunkS = (lane & 7) ^ srow;    // pre-swizzled global 16B chunk
  const __hip_bfloat16* aSrcQ[4];
  const __hip_bfloat16* bSrcQ[4];
#pragma unroll
  for (int q = 0; q < 4; q++) {
    const int arow = wid * 32 + q * 8 + srow;
    int brow = n0 + arow; if (brow > N - 1) brow = N - 1;
    aSrcQ[q] = A + (size_t)(m0 + arow) * Ks + chunkS * 8;
    bSrcQ[q] = Bt + (size_t)brow * Ks + chunkS * 8;
  }

  f32x4 acc[4][4];
#pragma unroll
  for (int m = 0; m < 4; m++)
#pragma unroll
    for (int n = 0; n < 4; n++) acc[m][n] = 0.f;

  // Read side: fragment row = (wr|wc)*64 + sub*16 + lr, desired chunk
  // kg*4 + (lane>>4); phys = chunk ^ (row&7) = chunk ^ (lr&7).
  const int lr = lane & 15;
  const int cbase = lane >> 4;  // 0..3
  int aoffk[2], boffk[2];
#pragma unroll
  for (int kg = 0; kg < 2; kg++) {
    const int phys = (kg * 4 + cbase) ^ (lr & 7);
    aoffk[kg] = (wr * 64 + lr) * 64 + phys * 8;
    boffk[kg] = (wc * 64 + lr) * 64 + phys * 8;
  }

#define STAGE(BUF, KT)                                              \
  do {                                                              \
    _Pragma("unroll") for (int q = 0; q < 4; q++) {                 \
      gll16(aSrcQ[q] + (KT), &As[BUF][(wid * 32 + q * 8) * 64]);    \
      gll16(bSrcQ[q] + (KT), &Bs[BUF][(wid * 32 + q * 8) * 64]);    \
    }                                                               \
  } while (0)

  STAGE(0, 0);
  int cur = 0;
  for (int kt = 0; kt < K; kt += 64) {
    const bool more = (kt + 64 < K);
    if (more) {
      STAGE(cur ^ 1, kt + 64);                       // issue next tile early
      asm volatile("s_waitcnt vmcnt(8)" ::: "memory");  // wait PREV tile only
    } else {
      asm volatile("s_waitcnt vmcnt(0)" ::: "memory");
    }
    __builtin_amdgcn_s_barrier();
#pragma unroll
    for (int kg = 0; kg < 2; kg++) {
      bf16x8 af[4], bfv[4];
#pragma unroll
      for (int m = 0; m < 4; m++) af[m] = *(const bf16x8*)&As[cur][aoffk[kg] + m * 16 * 64];
#pragma unroll
      for (int n = 0; n < 4; n++) bfv[n] = *(const bf16x8*)&Bs[cur][boffk[kg] + n * 16 * 64];
#pragma unroll
      for (int m = 0; m < 4; m++)
#pragma unroll
        for (int n = 0; n < 4; n++)
          acc[m][n] = __builtin_amdgcn_mfma_f32_16x16x32_bf16(af[m], bfv[n], acc[m][n], 0, 0, 0);
    }
    __builtin_amdgcn_s_barrier();   // all reads done -> next STAGE may overwrite
    cur ^= 1;
  }
#undef STAGE

  const int r4 = (lane >> 4) * 4;
#pragma unroll
  for (int m = 0; m < 4; m++) {
#pragma unroll
    for (int n = 0; n < 4; n++) {
      const int gn = n0 + wc * 64 + n * 16 + lr;
      if (gn < N) {
#pragma unroll
        for (int r = 0; r < 4; r++) {
          const int gm = m0 + wr * 64 + m * 16 + r4 + r;
          const size_t idx = (size_t)gm * N + gn;
          const float v = acc[m][n][r];
          switch (epi) {
            case 0: ((__hip_bfloat16*)Cz)[idx] = __float2bfloat16(v); break;
            case 1: ((__hip_bfloat16*)Cz)[idx] = __float2bfloat16(v / (1.f + expf(-v))); break;
            case 2: ((float*)Cz)[idx] = tanhf(v); break;
            case 3: ((__hip_bfloat16*)Cz)[idx] = __float2bfloat16(tanhf(v)); break;
            case 4: {
              float wv = v + aux[gn];
              wv = fminf(fmaxf(wv, -9.72f), 2.27f);
              ((float*)Cz)[idx] = expf(-expf(wv));
            } break;
            case 5: ((float*)Cz)[idx] = v + aux[idx]; break;
            case 6: ((float*)Cz)[idx] = v; break;
          }
        }
      }
    }
  }
}

// ---------- split-K combines ----------
__global__ __launch_bounds__(256) void comb8_tanh_f32(const float* __restrict__ p,
                                                      float* __restrict__ o, int n) {
  const int i = blockIdx.x * 256 + threadIdx.x;
  float s = 0.f;
#pragma unroll
  for (int k = 0; k < 8; k++) s += p[(size_t)k * n + i];
  o[i] = tanhf(s);
}

__global__ __launch_bounds__(256) void comb8_tanh_bf16(const float* __restrict__ p,
                                                       __hip_bfloat16* __restrict__ o, int n) {
  const int i = blockIdx.x * 256 + threadIdx.x;
  float s = 0.f;
#pragma unroll
  for (int k = 0; k < 8; k++) s += p[(size_t)k * n + i];
  o[i] = __float2bfloat16(tanhf(s));
}

// ---------- decay: rt[c][h][t][j] = r * cumA(t-1)  (bf16) ; Ptot[c][h][j] ----------
__global__ __launch_bounds__(64) void decay_kernel(const __hip_bfloat16* __restrict__ rb,
                                                   const float* __restrict__ td,
                                                   __hip_bfloat16* __restrict__ rt,
                                                   float* __restrict__ Ptot) {
  const int blk = blockIdx.x;  // c*NHEAD + h
  const int c = blk >> 5, h = blk & 31;
  const int j = threadIdx.x;
  const int hb = h * HSZ;
  const int t0 = c * CT;
  float A = 1.f;
#pragma unroll 4
  for (int t = 0; t < CT; t++) {
    const size_t rowb = (size_t)(t0 + t) * HDIM + hb;
    rt[(((size_t)c * NHEAD + h) * CT + t) * HSZ + j] =
        __float2bfloat16(__bfloat162float(rb[rowb + j]) * A);
    A *= td[rowb + j];
  }
  Ptot[((size_t)c * NHEAD + h) * HSZ + j] = A;
}

// ---------- single local scan pass: zero-init per chunk; 4-way j-split ----------
// Uses lgkmcnt-only barriers (cross-wave data flows via LDS only) so the
// global k/r/td/v loads stay in flight across timesteps.
__global__ __launch_bounds__(256) void scan_local_kernel(const __hip_bfloat16* __restrict__ kb,
                                                         const __hip_bfloat16* __restrict__ rb,
                                                         const float* __restrict__ td,
                                                         const __hip_bfloat16* __restrict__ vb,
                                                         float* __restrict__ wkv,
                                                         float* __restrict__ qT) {
  const int blk = blockIdx.x;           // c*NHEAD + h
  const int c = blk >> 5, h = blk & 31;
  const int w = threadIdx.x >> 6;       // j-quarter 0..3
  const int i = threadIdx.x & 63;       // lane = output row
  __shared__ float plds[2][4][64];

  float s[16];
#pragma unroll
  for (int q = 0; q < 16; q++) s[q] = 0.f;

  const int t0 = c * CT;
  const int hb = h * HSZ;

  for (int t = 0; t < CT; t++) {
    const size_t rowb = (size_t)(t0 + t) * HDIM + hb;
    const unsigned* kw = (const unsigned*)(kb + rowb + w * 16);  // 8 dwords (uniform)
    const unsigned* rw = (const unsigned*)(rb + rowb + w * 16);
    const float* tdw = td + rowb + w * 16;
    const float vi = __bfloat162float(vb[rowb + i]);
    float p = 0.f;
#pragma unroll
    for (int m = 0; m < 8; m++) {
      const unsigned kpair = kw[m];
      const unsigned rpair = rw[m];
      const float k0 = __builtin_bit_cast(float, kpair << 16);
      const float k1 = __builtin_bit_cast(float, kpair & 0xffff0000u);
      const float r0 = __builtin_bit_cast(float, rpair << 16);
      const float r1 = __builtin_bit_cast(float, rpair & 0xffff0000u);
      const float td0 = tdw[2 * m];
      const float td1 = tdw[2 * m + 1];
      const float kv0 = vi * k0;
      const float kv1 = vi * k1;
      p = fmaf(r0, s[2 * m], p);
      p = fmaf(r1, s[2 * m + 1], p);
      s[2 * m] = fmaf(s[2 * m], td0, kv0);
      s[2 * m + 1] = fmaf(s[2 * m + 1], td1, kv1);
    }
    plds[t & 1][w][i] = p;
    asm volatile("s_waitcnt lgkmcnt(0)" ::: "memory");  // LDS write visible
    __builtin_amdgcn_s_barrier();                        // no vmcnt drain
    if (w == 0) {
      wkv[rowb + i] = plds[t & 1][0][i] + plds[t & 1][1][i] +
                      plds[t & 1][2][i] + plds[t & 1][3][i];
    }
  }
  float* qbase = qT + (((size_t)c * NHEAD + h) * HSZ + w * 16) * HSZ + i;
#pragma unroll
  for (int q = 0; q < 16; q++) qbase[(size_t)q * HSZ] = s[q];
}

// ---------- sequential chunk combine: s0b (bf16) per chunk + s2out ----------
__global__ __launch_bounds__(64) void scan_s_kernel(const float* __restrict__ qT,
                                                    const float* __restrict__ Ptot,
                                                    const float* __restrict__ s2in,
                                                    __hip_bfloat16* __restrict__ s0b,
                                                    float* __restrict__ s2out) {
  const int h = blockIdx.x, i = blockIdx.y, j = threadIdx.x;
  float s = s2in[((size_t)h * HSZ + i) * HSZ + j];
#pragma unroll 4
  for (int c = 0; c < NC; c++) {
    s0b[(((size_t)c * NHEAD + h) * HSZ + i) * HSZ + j] = __float2bfloat16(s);
    s = fmaf(s, Ptot[((size_t)c * NHEAD + h) * HSZ + j],
             qT[(((size_t)c * NHEAD + h) * HSZ + j) * HSZ + i]);
  }
  s2out[((size_t)h * HSZ + i) * HSZ + j] = s;
}

// ---------- correction GEMM: wkv[c*CT+t][h][i] += sum_j rt[t][j] * s0b[i][j] ----------
__global__ __launch_bounds__(256) void corr_kernel(const __hip_bfloat16* __restrict__ rt,
                                                   const __hip_bfloat16* __restrict__ s0b,
                                                   float* __restrict__ wkv) {
  const int c = blockIdx.x, h = blockIdx.y;
  const int w = threadIdx.x >> 6;   // n-tile (i)
  const int lane = threadIdx.x & 63;
  const int lr = lane & 15, lk = (lane >> 4) * 8;
  const __hip_bfloat16* rbase = rt + (((size_t)c * NHEAD + h) * CT) * HSZ;
  const __hip_bfloat16* sbase = s0b + (((size_t)c * NHEAD + h) * HSZ) * HSZ;
  float* wbase = wkv + (size_t)(c * CT) * HDIM + h * HSZ;
#pragma unroll
  for (int mt = 0; mt < CT / 16; mt++) {
    f32x4 acc = {0.f, 0.f, 0.f, 0.f};
#pragma unroll
    for (int ks = 0; ks < 2; ks++) {
      bf16x8 af = *(const bf16x8*)(rbase + (size_t)(mt * 16 + lr) * HSZ + ks * 32 + lk);
      bf16x8 bf = *(const bf16x8*)(sbase + (size_t)(w * 16 + lr) * HSZ + ks * 32 + lk);
      acc = __builtin_amdgcn_mfma_f32_16x16x32_bf16(af, bf, acc, 0, 0, 0);
    }
    const int row = mt * 16 + (lane >> 4) * 4;
    const int col = w * 16 + lr;
#pragma unroll
    for (int r = 0; r < 4; r++)
      wbase[(size_t)(row + r) * HDIM + col] += acc[r];
  }
}

// ---------- group norm over HS (+diag wkv term) + scale/bias + gate ----------
__global__ __launch_bounds__(256) void gnorm_kernel(const float* __restrict__ wkv,
                                                    const __hip_bfloat16* __restrict__ kb,
                                                    const __hip_bfloat16* __restrict__ rb,
                                                    const float* __restrict__ tf,
                                                    const __hip_bfloat16* __restrict__ vb,
                                                    const __hip_bfloat16* __restrict__ gb,
                                                    const float* __restrict__ lnw,
                                                    const float* __restrict__ lnb,
                                                    __hip_bfloat16* __restrict__ yA) {
  const int t = blockIdx.x;
  const int wid = threadIdx.x >> 6, j = threadIdx.x & 63;
  const int h = blockIdx.y * 4 + wid;
  const size_t idx = (size_t)t * HDIM + h * HSZ + j;
  const float kj = __bfloat162float(kb[idx]);
  const float rj = __bfloat162float(rb[idx]);
  const float dg = waveRedSum(rj * tf[h * HSZ + j] * kj);
  const float v = wkv[idx] + dg * __bfloat162float(vb[idx]);
  const float mu = waveRedSum(v) * (1.f / HSZ);
  const float d = v - mu;
  const float var = waveRedSum(d * d) * (1.f / HSZ);
  float y = d * rsqrtf(var + 1e-5f);
  y = y * lnw[h * HSZ + j] + lnb[h * HSZ + j];
  y *= __bfloat162float(gb[idx]);
  yA[idx] = __float2bfloat16(y);
}

extern "C" void kernel_launch(void* const* d_in, const int* in_sizes, int n_in,
                              void* d_out, int out_size, void* d_ws, size_t ws_size,
                              hipStream_t stream) {
  (void)in_sizes; (void)n_in; (void)out_size; (void)ws_size;

  const float* x    = (const float*)d_in[0];
  const float* s1   = (const float*)d_in[1];
  const float* s2   = (const float*)d_in[2];
  const float* ln1w = (const float*)d_in[3];
  const float* ln1b = (const float*)d_in[4];
  const float* tmx  = (const float*)d_in[5];
  const float* tmaa = (const float*)d_in[6];
  const float* w1   = (const float*)d_in[7];
  const float* w2   = (const float*)d_in[8];
  const float* dw1  = (const float*)d_in[9];
  const float* dw2  = (const float*)d_in[10];
  const float* dp   = (const float*)d_in[11];
  const float* tf   = (const float*)d_in[12];
  const float* Wr   = (const float*)d_in[13];
  const float* Wk   = (const float*)d_in[14];
  const float* Wv   = (const float*)d_in[15];
  const float* Wg   = (const float*)d_in[16];
  const float* Wo   = (const float*)d_in[17];
  const float* lnxw = (const float*)d_in[18];
  const float* lnxb = (const float*)d_in[19];

  float* out0  = (float*)d_out;
  float* s1out = out0 + (size_t)TLEN * HDIM;
  float* s2out = s1out + HDIM;

  char* wp = (char*)d_ws;
  size_t off = 0;
  auto carve = [&](size_t bytes) -> void* {
    void* r = wp + off;
    off += (bytes + 255) & ~(size_t)255;
    return r;
  };

  __hip_bfloat16* wrt  = (__hip_bfloat16*)carve((size_t)HDIM * HDIM * 2);
  __hip_bfloat16* wkt  = (__hip_bfloat16*)carve((size_t)HDIM * HDIM * 2);
  __hip_bfloat16* wvt  = (__hip_bfloat16*)carve((size_t)HDIM * HDIM * 2);
  __hip_bfloat16* wgt  = (__hip_bfloat16*)carve((size_t)HDIM * HDIM * 2);
  __hip_bfloat16* wot  = (__hip_bfloat16*)carve((size_t)HDIM * HDIM * 2);
  __hip_bfloat16* w1t  = (__hip_bfloat16*)carve((size_t)160 * HDIM * 2);
  __hip_bfloat16* dw1t = (__hip_bfloat16*)carve((size_t)64 * HDIM * 2);
  __hip_bfloat16* dw2t = (__hip_bfloat16*)carve((size_t)HDIM * 64 * 2);
  float* xl            = (float*)carve((size_t)THE * 4);
  __hip_bfloat16* xxx  = (__hip_bfloat16*)carve((size_t)THE * 2);
  float* t5            = (float*)carve((size_t)TLEN * 160 * 4);
  __hip_bfloat16* x5b  = (__hip_bfloat16*)carve((size_t)5 * THE * 2);
  __hip_bfloat16* rb   = (__hip_bfloat16*)carve((size_t)THE * 2);
  __hip_bfloat16* kb   = (__hip_bfloat16*)carve((size_t)THE * 2);
  __hip_bfloat16* vb   = (__hip_bfloat16*)carve((size_t)THE * 2);
  __hip_bfloat16* gb   = (__hip_bfloat16*)carve((size_t)THE * 2);
  __hip_bfloat16* tw   = (__hip_bfloat16*)carve((size_t)TLEN * 64 * 2);
  float* td            = (float*)carve((size_t)THE * 4);
  float* wkv           = (float*)carve((size_t)THE * 4);
  __hip_bfloat16* yA   = (__hip_bfloat16*)carve((size_t)THE * 2);

  // Aliased scratch (all regions dead at time of use):
  //   qT   (16MB) <- x5b       (dead after G4/G5; used in scan stage)
  //   rt   ( 4MB) <- xl        (dead after mix)
  //   s0b  ( 8MB) <- td        (dead after scan_local)
  //   Ptot (256KB)<- t5        (dead after mix)
  //   pg1  (5.2MB)<- td region (free until G5 writes td)
  //   pg4  ( 2MB) <- xxx       (dead after G1)
  float* qT            = (float*)x5b;
  __hip_bfloat16* rt   = (__hip_bfloat16*)xl;
  __hip_bfloat16* s0b  = (__hip_bfloat16*)td;
  float* Ptot          = (float*)t5;
  float* pg1           = (float*)td;
  float* pg4           = (float*)xxx;

  // K0: convert + transpose all GEMM weights to bf16 [N][K]
  TrArgs ta;
  const float* srcs[8] = {Wr, Wk, Wv, Wg, Wo, w1, dw1, dw2};
  __hip_bfloat16* dsts[8] = {wrt, wkt, wvt, wgt, wot, w1t, dw1t, dw2t};
  const int Rs[8] = {HDIM, HDIM, HDIM, HDIM, HDIM, HDIM, HDIM, 64};
  const int Cs[8] = {HDIM, HDIM, HDIM, HDIM, HDIM, 160, 64, HDIM};
  for (int z = 0; z < 8; z++) { ta.src[z] = srcs[z]; ta.dst[z] = dsts[z]; ta.R[z] = Rs[z]; ta.C[z] = Cs[z]; }
  transp_kernel<<<dim3(64, 64, 8), 256, 0, stream>>>(ta);

  // K1: layernorm
  ln1_kernel<<<dim3(TLEN), 256, 0, stream>>>(x, ln1w, ln1b, xl, s1out);

  // K2: token shift -> xxx (bf16)
  tokshift_kernel<<<dim3(TLEN, HDIM / 256), 256, 0, stream>>>(xl, s1, tmx, xxx);

  // G1: t5 = tanh(xxx @ w1)  (M=1024, N=160, K=2048) -- split-K=8
  {
    GemmArgs g{};
    for (int ks = 0; ks < 8; ks++) {
      g.A[ks] = xxx + ks * 256;
      g.B[ks] = w1t + ks * 256;
      g.C[ks] = pg1 + (size_t)ks * TLEN * 160;
      g.epi[ks] = 6;
    }
    g.M = TLEN; g.N = 160; g.K = 256; g.Ks = HDIM;
    gemm_bt<<<dim3(TLEN / 128, 2, 8), 256, 0, stream>>>(g);
    comb8_tanh_f32<<<dim3(TLEN * 160 / 256), 256, 0, stream>>>(pg1, t5, TLEN * 160);
  }

  // K4: mix + x5 (5 planes, bf16)
  mix_kernel<<<dim3(HDIM / 256, TLEN / 8), 256, 0, stream>>>(t5, xl, s1, w2, tmaa, x5b);

  // G2: r, k, v, g  (batched z=4)
  {
    GemmArgs g{};
    g.A[0] = x5b + (size_t)3 * THE; g.B[0] = wrt; g.C[0] = rb; g.epi[0] = 0;
    g.A[1] = x5b + (size_t)1 * THE; g.B[1] = wkt; g.C[1] = kb; g.epi[1] = 0;
    g.A[2] = x5b + (size_t)2 * THE; g.B[2] = wvt; g.C[2] = vb; g.epi[2] = 0;
    g.A[3] = x5b + (size_t)4 * THE; g.B[3] = wgt; g.C[3] = gb; g.epi[3] = 1;
    g.M = TLEN; g.N = HDIM; g.K = HDIM; g.Ks = HDIM;
    gemm_bt<<<dim3(TLEN / 128, HDIM / 128, 4), 256, 0, stream>>>(g);
  }

  // G4: tw = tanh(mw @ dw1)  (N=64) -- split-K=8
  {
    GemmArgs g{};
    for (int ks = 0; ks < 8; ks++) {
      g.A[ks] = x5b + ks * 256;          // plane 0 = mw
      g.B[ks] = dw1t + ks * 256;
      g.C[ks] = pg4 + (size_t)ks * TLEN * 64;
      g.epi[ks] = 6;
    }
    g.M = TLEN; g.N = 64; g.K = 256; g.Ks = HDIM;
    gemm_bt<<<dim3(TLEN / 128, 1, 8), 256, 0, stream>>>(g);
    comb8_tanh_bf16<<<dim3(TLEN * 64 / 256), 256, 0, stream>>>(pg4, tw, TLEN * 64);
  }

  // G5: td = exp(-exp(clip(tw @ dw2 + p)))  (K=64)
  {
    GemmArgs g{};
    g.A[0] = tw; g.B[0] = dw2t; g.C[0] = td; g.aux[0] = dp; g.epi[0] = 4;
    g.M = TLEN; g.N = HDIM; g.K = 64; g.Ks = 64;
    gemm_bt<<<dim3(TLEN / 128, HDIM / 128, 1), 256, 0, stream>>>(g);
  }

  // Scan stage: decay factors, single local pass, chunk combine, MFMA correction
  decay_kernel<<<dim3(NC * NHEAD), 64, 0, stream>>>(rb, td, rt, Ptot);
  scan_local_kernel<<<dim3(NC * NHEAD), 256, 0, stream>>>(kb, rb, td, vb, wkv, qT);
  scan_s_kernel<<<dim3(NHEAD, HSZ), 64, 0, stream>>>(qT, Ptot, s2, s0b, s2out);
  corr_kernel<<<dim3(NC, NHEAD), 256, 0, stream>>>(rt, s0b, wkv);

  // K7: group-norm (+diag term) + gate -> yA (bf16)
  gnorm_kernel<<<dim3(TLEN, NHEAD / 4), 256, 0, stream>>>(wkv, kb, rb, tf, vb, gb, lnxw, lnxb, yA);

  // G6: out = x + yA @ W_o  (direct epilogue, no split-K: split gave ~0 GEMM
  // gain in r8 and cost a 40MB combine pass)
  {
    GemmArgs g{};
    g.A[0] = yA; g.B[0] = wot; g.C[0] = out0; g.aux[0] = x; g.epi[0] = 5;
    g.M = TLEN; g.N = HDIM; g.K = HDIM; g.Ks = HDIM;
    gemm_bt<<<dim3(TLEN / 128, HDIM / 128, 1), 256, 0, stream>>>(g);
  }
}

// Round 11
// 289.818 us; speedup vs baseline: 1.0649x; 1.0649x over previous
//
#include <hip/hip_runtime.h>
#include <hip/hip_bf16.h>
#include <math.h>

#define TLEN 1024
#define HDIM 2048
#define NHEAD 32
#define HSZ 64
#define THE (TLEN * HDIM)
#define NC 32          // scan chunks
#define CT (TLEN / NC) // 32 timesteps per chunk

typedef __attribute__((ext_vector_type(8))) short bf16x8;
typedef __attribute__((ext_vector_type(4))) float f32x4;

__device__ __forceinline__ float waveRedSum(float v) {
#pragma unroll
  for (int off = 32; off > 0; off >>= 1) v += __shfl_xor(v, off, 64);
  return v;
}

__device__ __forceinline__ void gll16(const __hip_bfloat16* g, __hip_bfloat16* l) {
  __builtin_amdgcn_global_load_lds(
      (const __attribute__((address_space(1))) void*)g,
      (__attribute__((address_space(3))) void*)l, 16, 0, 0);
}

// ---------- weight convert + transpose: src f32 [R][C] -> dst bf16 [C][R] ----------
struct TrArgs {
  const float* src[8];
  __hip_bfloat16* dst[8];
  int R[8];
  int C[8];
};

__global__ __launch_bounds__(256) void transp_kernel(TrArgs ta) {
  const int z = blockIdx.z;
  const int R = ta.R[z], C = ta.C[z];
  const int c0 = blockIdx.x * 32, r0 = blockIdx.y * 32;
  if (c0 >= C || r0 >= R) return;
  __shared__ float tile[32][33];
  const int tx = threadIdx.x & 31, ty = threadIdx.x >> 5;
  const float* src = ta.src[z];
  __hip_bfloat16* dst = ta.dst[z];
#pragma unroll
  for (int i = 0; i < 4; i++)
    tile[ty + i * 8][tx] = src[(size_t)(r0 + ty + i * 8) * C + c0 + tx];
  __syncthreads();
#pragma unroll
  for (int i = 0; i < 4; i++)
    dst[(size_t)(c0 + ty + i * 8) * R + r0 + tx] = __float2bfloat16(tile[tx][ty + i * 8]);
}

// ---------- LayerNorm (row) + state1_out ----------
__global__ __launch_bounds__(256) void ln1_kernel(const float* __restrict__ x,
                                                  const float* __restrict__ w,
                                                  const float* __restrict__ b,
                                                  float* __restrict__ xl,
                                                  float* __restrict__ s1out) {
  const int t = blockIdx.x;
  const int tid = threadIdx.x;
  const int wid = tid >> 6, lane = tid & 63;
  const float4* xr = (const float4*)(x + (size_t)t * HDIM);
  float4 a = xr[tid];
  float4 c = xr[tid + 256];
  float va[8] = {a.x, a.y, a.z, a.w, c.x, c.y, c.z, c.w};
  float sum = 0.f;
#pragma unroll
  for (int i = 0; i < 8; i++) sum += va[i];
  sum = waveRedSum(sum);
  __shared__ float red[8];
  if (lane == 0) red[wid] = sum;
  __syncthreads();
  const float mu = (red[0] + red[1] + red[2] + red[3]) * (1.f / HDIM);
  float vs = 0.f;
#pragma unroll
  for (int i = 0; i < 8; i++) { float d = va[i] - mu; vs += d * d; }
  vs = waveRedSum(vs);
  if (lane == 0) red[4 + wid] = vs;
  __syncthreads();
  const float rstd = rsqrtf((red[4] + red[5] + red[6] + red[7]) * (1.f / HDIM) + 1e-5f);
  float* xrow = xl + (size_t)t * HDIM;
#pragma unroll
  for (int i = 0; i < 8; i++) {
    const int idx = (i < 4) ? (4 * tid + i) : (1024 + 4 * tid + (i - 4));
    const float o = (va[i] - mu) * rstd * w[idx] + b[idx];
    xrow[idx] = o;
    if (t == TLEN - 1) s1out[idx] = o;
  }
}

// ---------- token shift: xxx = xl + (past - xl) * time_maa_x ----------
__global__ __launch_bounds__(256) void tokshift_kernel(const float* __restrict__ xl,
                                                       const float* __restrict__ s1,
                                                       const float* __restrict__ tmx,
                                                       __hip_bfloat16* __restrict__ xxx) {
  const int t = blockIdx.x;
  const int h = blockIdx.y * 256 + threadIdx.x;
  const float cur = xl[(size_t)t * HDIM + h];
  const float past = (t > 0) ? xl[(size_t)(t - 1) * HDIM + h] : s1[h];
  xxx[(size_t)t * HDIM + h] = __float2bfloat16(cur + (past - cur) * tmx[h]);
}

// ---------- mix: x5[f] = xl + sx * (t5[f] @ w2[f] + time_maa[f]) ----------
__global__ __launch_bounds__(256) void mix_kernel(const float* __restrict__ t5,
                                                  const float* __restrict__ xl,
                                                  const float* __restrict__ s1,
                                                  const float* __restrict__ w2,
                                                  const float* __restrict__ maa,
                                                  __hip_bfloat16* __restrict__ x5b) {
  const int h = blockIdx.x * 256 + threadIdx.x;
  const int t0 = blockIdx.y * 8;
  __shared__ float t5L[8 * 160];
  for (int i = threadIdx.x; i < 8 * 160; i += 256) {
    const int rr = i / 160, cc = i - rr * 160;
    t5L[i] = t5[(size_t)(t0 + rr) * 160 + cc];
  }
  __syncthreads();
  float mixv[8][5];
#pragma unroll
  for (int ts = 0; ts < 8; ts++)
#pragma unroll
    for (int f = 0; f < 5; f++) mixv[ts][f] = 0.f;
#pragma unroll
  for (int f = 0; f < 5; f++) {
#pragma unroll 4
    for (int m = 0; m < 32; m++) {
      const float w2v = w2[(size_t)(f * 32 + m) * HDIM + h];
#pragma unroll
      for (int ts = 0; ts < 8; ts++) mixv[ts][f] += t5L[ts * 160 + f * 32 + m] * w2v;
    }
  }
#pragma unroll
  for (int ts = 0; ts < 8; ts++) {
    const int t = t0 + ts;
    const float cur = xl[(size_t)t * HDIM + h];
    const float past = (t > 0) ? xl[(size_t)(t - 1) * HDIM + h] : s1[h];
    const float sx = past - cur;
#pragma unroll
    for (int f = 0; f < 5; f++) {
      const float v = cur + sx * (mixv[ts][f] + maa[(size_t)f * HDIM + h]);
      x5b[(size_t)f * THE + (size_t)t * HDIM + h] = __float2bfloat16(v);
    }
  }
}

// ---------- batched MFMA GEMM: C[z] = epi( A[z](MxK) @ Bt[z](NxK)^T ) ----------
// BK=64, double-buffered LDS, counted-vmcnt pipeline (prefetch stays in flight
// across barriers), bank-conflict-free XOR swizzle. [round-8 proven structure]
// K = loop length (may be a split-K slice); Ks = row stride of A and Bt.
// epi: 0=bf16, 1=bf16 silu, 2=f32 tanh, 3=bf16 tanh, 4=f32 td, 5=f32 +residual, 6=f32 raw partial
struct GemmArgs {
  const __hip_bfloat16* A[8];
  const __hip_bfloat16* B[8];
  void* C[8];
  const float* aux[8];
  int epi[8];
  int M, N, K, Ks;
};

__global__ __launch_bounds__(256) void gemm_bt(GemmArgs ga) {
  const int z = blockIdx.z;
  const __hip_bfloat16* __restrict__ A = ga.A[z];
  const __hip_bfloat16* __restrict__ Bt = ga.B[z];
  const int N = ga.N, K = ga.K, Ks = ga.Ks;
  const int epi = ga.epi[z];
  const float* __restrict__ aux = ga.aux[z];
  void* Cz = ga.C[z];

  // [2 buffers][128 rows][64 cols] bf16 (128B rows)
  __shared__ __align__(16) __hip_bfloat16 As[2][128 * 64];
  __shared__ __align__(16) __hip_bfloat16 Bs[2][128 * 64];

  const int tid = threadIdx.x;
  const int wid = tid >> 6;
  const int lane = tid & 63;

  // XCD-aware swizzle for the 8x16 grids: cluster all 8 m-blocks of one
  // n-panel onto a single XCD so the B panel stays L2-resident.
  int bx = blockIdx.x, by = blockIdx.y;
  if (gridDim.x == 8 && gridDim.y == 16) {
    const int flat = bx + 8 * by;  // 0..127
    const int xcd = flat & 7, rem = flat >> 3;
    bx = rem & 7;
    by = xcd + 8 * (rem >> 3);
  }
  const int m0 = bx * 128;
  const int n0 = by * 128;
  const int wr = wid >> 1, wc = wid & 1;

  // Staging: call q (per wave) covers rows wid*32+q*8 .. +7.
  // lane l -> row +(l>>3), LDS slot l&7 (16B slots in a 128B row).
  // Pre-swizzled source: phys slot p of row r holds global chunk p ^ (r&7).
  const int srow = lane >> 3;              // 0..7
  const int chunkS = (lane & 7) ^ srow;    // pre-swizzled global 16B chunk
  const __hip_bfloat16* aSrcQ[4];
  const __hip_bfloat16* bSrcQ[4];
#pragma unroll
  for (int q = 0; q < 4; q++) {
    const int arow = wid * 32 + q * 8 + srow;
    int brow = n0 + arow; if (brow > N - 1) brow = N - 1;
    aSrcQ[q] = A + (size_t)(m0 + arow) * Ks + chunkS * 8;
    bSrcQ[q] = Bt + (size_t)brow * Ks + chunkS * 8;
  }

  f32x4 acc[4][4];
#pragma unroll
  for (int m = 0; m < 4; m++)
#pragma unroll
    for (int n = 0; n < 4; n++) acc[m][n] = 0.f;

  // Read side: fragment row = (wr|wc)*64 + sub*16 + lr, desired chunk
  // kg*4 + (lane>>4); phys = chunk ^ (row&7) = chunk ^ (lr&7).
  const int lr = lane & 15;
  const int cbase = lane >> 4;  // 0..3
  int aoffk[2], boffk[2];
#pragma unroll
  for (int kg = 0; kg < 2; kg++) {
    const int phys = (kg * 4 + cbase) ^ (lr & 7);
    aoffk[kg] = (wr * 64 + lr) * 64 + phys * 8;
    boffk[kg] = (wc * 64 + lr) * 64 + phys * 8;
  }

#define STAGE(BUF, KT)                                              \
  do {                                                              \
    _Pragma("unroll") for (int q = 0; q < 4; q++) {                 \
      gll16(aSrcQ[q] + (KT), &As[BUF][(wid * 32 + q * 8) * 64]);    \
      gll16(bSrcQ[q] + (KT), &Bs[BUF][(wid * 32 + q * 8) * 64]);    \
    }                                                               \
  } while (0)

  STAGE(0, 0);
  int cur = 0;
  for (int kt = 0; kt < K; kt += 64) {
    const bool more = (kt + 64 < K);
    if (more) {
      STAGE(cur ^ 1, kt + 64);                       // issue next tile early
      asm volatile("s_waitcnt vmcnt(8)" ::: "memory");  // wait PREV tile only
    } else {
      asm volatile("s_waitcnt vmcnt(0)" ::: "memory");
    }
    __builtin_amdgcn_s_barrier();
#pragma unroll
    for (int kg = 0; kg < 2; kg++) {
      bf16x8 af[4], bfv[4];
#pragma unroll
      for (int m = 0; m < 4; m++) af[m] = *(const bf16x8*)&As[cur][aoffk[kg] + m * 16 * 64];
#pragma unroll
      for (int n = 0; n < 4; n++) bfv[n] = *(const bf16x8*)&Bs[cur][boffk[kg] + n * 16 * 64];
#pragma unroll
      for (int m = 0; m < 4; m++)
#pragma unroll
        for (int n = 0; n < 4; n++)
          acc[m][n] = __builtin_amdgcn_mfma_f32_16x16x32_bf16(af[m], bfv[n], acc[m][n], 0, 0, 0);
    }
    __builtin_amdgcn_s_barrier();   // all reads done -> next STAGE may overwrite
    cur ^= 1;
  }
#undef STAGE

  const int r4 = (lane >> 4) * 4;
#pragma unroll
  for (int m = 0; m < 4; m++) {
#pragma unroll
    for (int n = 0; n < 4; n++) {
      const int gn = n0 + wc * 64 + n * 16 + lr;
      if (gn < N) {
#pragma unroll
        for (int r = 0; r < 4; r++) {
          const int gm = m0 + wr * 64 + m * 16 + r4 + r;
          const size_t idx = (size_t)gm * N + gn;
          const float v = acc[m][n][r];
          switch (epi) {
            case 0: ((__hip_bfloat16*)Cz)[idx] = __float2bfloat16(v); break;
            case 1: ((__hip_bfloat16*)Cz)[idx] = __float2bfloat16(v / (1.f + expf(-v))); break;
            case 2: ((float*)Cz)[idx] = tanhf(v); break;
            case 3: ((__hip_bfloat16*)Cz)[idx] = __float2bfloat16(tanhf(v)); break;
            case 4: {
              float wv = v + aux[gn];
              wv = fminf(fmaxf(wv, -9.72f), 2.27f);
              ((float*)Cz)[idx] = expf(-expf(wv));
            } break;
            case 5: ((float*)Cz)[idx] = v + aux[idx]; break;
            case 6: ((float*)Cz)[idx] = v; break;
          }
        }
      }
    }
  }
}

// ---------- split-K combines ----------
__global__ __launch_bounds__(256) void comb8_tanh_f32(const float* __restrict__ p,
                                                      float* __restrict__ o, int n) {
  const int i = blockIdx.x * 256 + threadIdx.x;
  float s = 0.f;
#pragma unroll
  for (int k = 0; k < 8; k++) s += p[(size_t)k * n + i];
  o[i] = tanhf(s);
}

__global__ __launch_bounds__(256) void comb8_tanh_bf16(const float* __restrict__ p,
                                                       __hip_bfloat16* __restrict__ o, int n) {
  const int i = blockIdx.x * 256 + threadIdx.x;
  float s = 0.f;
#pragma unroll
  for (int k = 0; k < 8; k++) s += p[(size_t)k * n + i];
  o[i] = __float2bfloat16(tanhf(s));
}

__global__ __launch_bounds__(256) void comb4_resid(const float* __restrict__ p,
                                                   const float* __restrict__ x,
                                                   float* __restrict__ o) {
  const int i = blockIdx.x * 256 + threadIdx.x;
  const float4 a = ((const float4*)p)[i];
  const float4 b = ((const float4*)(p + THE))[i];
  const float4 c = ((const float4*)(p + 2 * (size_t)THE))[i];
  const float4 d = ((const float4*)(p + 3 * (size_t)THE))[i];
  const float4 e = ((const float4*)x)[i];
  ((float4*)o)[i] = make_float4(a.x + b.x + c.x + d.x + e.x,
                                a.y + b.y + c.y + d.y + e.y,
                                a.z + b.z + c.z + d.z + e.z,
                                a.w + b.w + c.w + d.w + e.w);
}

// ---------- decay: rt[c][h][t][j] = r * cumA(t-1)  (bf16) ; Ptot[c][h][j] ----------
__global__ __launch_bounds__(64) void decay_kernel(const __hip_bfloat16* __restrict__ rb,
                                                   const float* __restrict__ td,
                                                   __hip_bfloat16* __restrict__ rt,
                                                   float* __restrict__ Ptot) {
  const int blk = blockIdx.x;  // c*NHEAD + h
  const int c = blk >> 5, h = blk & 31;
  const int j = threadIdx.x;
  const int hb = h * HSZ;
  const int t0 = c * CT;
  float A = 1.f;
  for (int t = 0; t < CT; t++) {
    const size_t rowb = (size_t)(t0 + t) * HDIM + hb;
    rt[(((size_t)c * NHEAD + h) * CT + t) * HSZ + j] =
        __float2bfloat16(__bfloat162float(rb[rowb + j]) * A);
    A *= td[rowb + j];
  }
  Ptot[((size_t)c * NHEAD + h) * HSZ + j] = A;
}

// ---------- single local scan pass: zero-init per chunk; 4-way j-split ----------
__global__ __launch_bounds__(256) void scan_local_kernel(const __hip_bfloat16* __restrict__ kb,
                                                         const __hip_bfloat16* __restrict__ rb,
                                                         const float* __restrict__ td,
                                                         const __hip_bfloat16* __restrict__ vb,
                                                         float* __restrict__ wkv,
                                                         float* __restrict__ qT) {
  const int blk = blockIdx.x;           // c*NHEAD + h
  const int c = blk >> 5, h = blk & 31;
  const int w = threadIdx.x >> 6;       // j-quarter 0..3
  const int i = threadIdx.x & 63;       // lane = output row
  __shared__ float plds[2][4][64];

  float s[16];
#pragma unroll
  for (int q = 0; q < 16; q++) s[q] = 0.f;

  const int t0 = c * CT;
  const int hb = h * HSZ;

  for (int t = 0; t < CT; t++) {
    const size_t rowb = (size_t)(t0 + t) * HDIM + hb;
    const unsigned* kw = (const unsigned*)(kb + rowb + w * 16);  // 8 dwords (uniform)
    const unsigned* rw = (const unsigned*)(rb + rowb + w * 16);
    const float* tdw = td + rowb + w * 16;
    const float vi = __bfloat162float(vb[rowb + i]);
    float p = 0.f;
#pragma unroll
    for (int m = 0; m < 8; m++) {
      const unsigned kpair = kw[m];
      const unsigned rpair = rw[m];
      const float k0 = __builtin_bit_cast(float, kpair << 16);
      const float k1 = __builtin_bit_cast(float, kpair & 0xffff0000u);
      const float r0 = __builtin_bit_cast(float, rpair << 16);
      const float r1 = __builtin_bit_cast(float, rpair & 0xffff0000u);
      const float td0 = tdw[2 * m];
      const float td1 = tdw[2 * m + 1];
      const float kv0 = vi * k0;
      const float kv1 = vi * k1;
      p = fmaf(r0, s[2 * m], p);
      p = fmaf(r1, s[2 * m + 1], p);
      s[2 * m] = fmaf(s[2 * m], td0, kv0);
      s[2 * m + 1] = fmaf(s[2 * m + 1], td1, kv1);
    }
    plds[t & 1][w][i] = p;
    __syncthreads();
    if (w == 0) {
      wkv[rowb + i] = plds[t & 1][0][i] + plds[t & 1][1][i] +
                      plds[t & 1][2][i] + plds[t & 1][3][i];
    }
  }
  float* qbase = qT + (((size_t)c * NHEAD + h) * HSZ + w * 16) * HSZ + i;
#pragma unroll
  for (int q = 0; q < 16; q++) qbase[(size_t)q * HSZ] = s[q];
}

// ---------- sequential chunk combine: s0b (bf16) per chunk + s2out ----------
__global__ __launch_bounds__(64) void scan_s_kernel(const float* __restrict__ qT,
                                                    const float* __restrict__ Ptot,
                                                    const float* __restrict__ s2in,
                                                    __hip_bfloat16* __restrict__ s0b,
                                                    float* __restrict__ s2out) {
  const int h = blockIdx.x, i = blockIdx.y, j = threadIdx.x;
  float s = s2in[((size_t)h * HSZ + i) * HSZ + j];
#pragma unroll 4
  for (int c = 0; c < NC; c++) {
    s0b[(((size_t)c * NHEAD + h) * HSZ + i) * HSZ + j] = __float2bfloat16(s);
    s = fmaf(s, Ptot[((size_t)c * NHEAD + h) * HSZ + j],
             qT[(((size_t)c * NHEAD + h) * HSZ + j) * HSZ + i]);
  }
  s2out[((size_t)h * HSZ + i) * HSZ + j] = s;
}

// ---------- correction GEMM: wkv[c*CT+t][h][i] += sum_j rt[t][j] * s0b[i][j] ----------
__global__ __launch_bounds__(256) void corr_kernel(const __hip_bfloat16* __restrict__ rt,
                                                   const __hip_bfloat16* __restrict__ s0b,
                                                   float* __restrict__ wkv) {
  const int c = blockIdx.x, h = blockIdx.y;
  const int w = threadIdx.x >> 6;   // n-tile (i)
  const int lane = threadIdx.x & 63;
  const int lr = lane & 15, lk = (lane >> 4) * 8;
  const __hip_bfloat16* rbase = rt + (((size_t)c * NHEAD + h) * CT) * HSZ;
  const __hip_bfloat16* sbase = s0b + (((size_t)c * NHEAD + h) * HSZ) * HSZ;
  float* wbase = wkv + (size_t)(c * CT) * HDIM + h * HSZ;
#pragma unroll
  for (int mt = 0; mt < CT / 16; mt++) {
    f32x4 acc = {0.f, 0.f, 0.f, 0.f};
#pragma unroll
    for (int ks = 0; ks < 2; ks++) {
      bf16x8 af = *(const bf16x8*)(rbase + (size_t)(mt * 16 + lr) * HSZ + ks * 32 + lk);
      bf16x8 bf = *(const bf16x8*)(sbase + (size_t)(w * 16 + lr) * HSZ + ks * 32 + lk);
      acc = __builtin_amdgcn_mfma_f32_16x16x32_bf16(af, bf, acc, 0, 0, 0);
    }
    const int row = mt * 16 + (lane >> 4) * 4;
    const int col = w * 16 + lr;
#pragma unroll
    for (int r = 0; r < 4; r++)
      wbase[(size_t)(row + r) * HDIM + col] += acc[r];
  }
}

// ---------- group norm over HS (+diag wkv term) + scale/bias + gate ----------
__global__ __launch_bounds__(256) void gnorm_kernel(const float* __restrict__ wkv,
                                                    const __hip_bfloat16* __restrict__ kb,
                                                    const __hip_bfloat16* __restrict__ rb,
                                                    const float* __restrict__ tf,
                                                    const __hip_bfloat16* __restrict__ vb,
                                                    const __hip_bfloat16* __restrict__ gb,
                                                    const float* __restrict__ lnw,
                                                    const float* __restrict__ lnb,
                                                    __hip_bfloat16* __restrict__ yA) {
  const int t = blockIdx.x;
  const int wid = threadIdx.x >> 6, j = threadIdx.x & 63;
  const int h = blockIdx.y * 4 + wid;
  const size_t idx = (size_t)t * HDIM + h * HSZ + j;
  const float kj = __bfloat162float(kb[idx]);
  const float rj = __bfloat162float(rb[idx]);
  const float dg = waveRedSum(rj * tf[h * HSZ + j] * kj);
  const float v = wkv[idx] + dg * __bfloat162float(vb[idx]);
  const float mu = waveRedSum(v) * (1.f / HSZ);
  const float d = v - mu;
  const float var = waveRedSum(d * d) * (1.f / HSZ);
  float y = d * rsqrtf(var + 1e-5f);
  y = y * lnw[h * HSZ + j] + lnb[h * HSZ + j];
  y *= __bfloat162float(gb[idx]);
  yA[idx] = __float2bfloat16(y);
}

extern "C" void kernel_launch(void* const* d_in, const int* in_sizes, int n_in,
                              void* d_out, int out_size, void* d_ws, size_t ws_size,
                              hipStream_t stream) {
  (void)in_sizes; (void)n_in; (void)out_size; (void)ws_size;

  const float* x    = (const float*)d_in[0];
  const float* s1   = (const float*)d_in[1];
  const float* s2   = (const float*)d_in[2];
  const float* ln1w = (const float*)d_in[3];
  const float* ln1b = (const float*)d_in[4];
  const float* tmx  = (const float*)d_in[5];
  const float* tmaa = (const float*)d_in[6];
  const float* w1   = (const float*)d_in[7];
  const float* w2   = (const float*)d_in[8];
  const float* dw1  = (const float*)d_in[9];
  const float* dw2  = (const float*)d_in[10];
  const float* dp   = (const float*)d_in[11];
  const float* tf   = (const float*)d_in[12];
  const float* Wr   = (const float*)d_in[13];
  const float* Wk   = (const float*)d_in[14];
  const float* Wv   = (const float*)d_in[15];
  const float* Wg   = (const float*)d_in[16];
  const float* Wo   = (const float*)d_in[17];
  const float* lnxw = (const float*)d_in[18];
  const float* lnxb = (const float*)d_in[19];

  float* out0  = (float*)d_out;
  float* s1out = out0 + (size_t)TLEN * HDIM;
  float* s2out = s1out + HDIM;

  char* wp = (char*)d_ws;
  size_t off = 0;
  auto carve = [&](size_t bytes) -> void* {
    void* r = wp + off;
    off += (bytes + 255) & ~(size_t)255;
    return r;
  };

  __hip_bfloat16* wrt  = (__hip_bfloat16*)carve((size_t)HDIM * HDIM * 2);
  __hip_bfloat16* wkt  = (__hip_bfloat16*)carve((size_t)HDIM * HDIM * 2);
  __hip_bfloat16* wvt  = (__hip_bfloat16*)carve((size_t)HDIM * HDIM * 2);
  __hip_bfloat16* wgt  = (__hip_bfloat16*)carve((size_t)HDIM * HDIM * 2);
  __hip_bfloat16* wot  = (__hip_bfloat16*)carve((size_t)HDIM * HDIM * 2);
  __hip_bfloat16* w1t  = (__hip_bfloat16*)carve((size_t)160 * HDIM * 2);
  __hip_bfloat16* dw1t = (__hip_bfloat16*)carve((size_t)64 * HDIM * 2);
  __hip_bfloat16* dw2t = (__hip_bfloat16*)carve((size_t)HDIM * 64 * 2);
  float* xl            = (float*)carve((size_t)THE * 4);
  __hip_bfloat16* xxx  = (__hip_bfloat16*)carve((size_t)THE * 2);
  float* t5            = (float*)carve((size_t)TLEN * 160 * 4);
  __hip_bfloat16* x5b  = (__hip_bfloat16*)carve((size_t)5 * THE * 2);
  __hip_bfloat16* rb   = (__hip_bfloat16*)carve((size_t)THE * 2);
  __hip_bfloat16* kb   = (__hip_bfloat16*)carve((size_t)THE * 2);
  __hip_bfloat16* vb   = (__hip_bfloat16*)carve((size_t)THE * 2);
  __hip_bfloat16* gb   = (__hip_bfloat16*)carve((size_t)THE * 2);
  __hip_bfloat16* tw   = (__hip_bfloat16*)carve((size_t)TLEN * 64 * 2);
  float* td            = (float*)carve((size_t)THE * 4);
  float* wkv           = (float*)carve((size_t)THE * 4);
  __hip_bfloat16* yA   = (__hip_bfloat16*)carve((size_t)THE * 2);

  // Aliased scratch (all regions dead at time of use):
  //   qT   (16MB) <- x5b       (dead after G4/G5; used in scan stage)
  //   rt   ( 4MB) <- xl        (dead after mix)
  //   s0b  ( 8MB) <- td        (dead after scan_local)
  //   Ptot (256KB)<- t5        (dead after mix)
  //   pg1  (5.2MB)<- td region (free until G5 writes td)
  //   pg4  ( 2MB) <- xxx       (dead after G1)
  //   pg6  (32MB) <- x5b+rb+kb+vb (contiguous carves; all dead after gnorm)
  float* qT            = (float*)x5b;
  __hip_bfloat16* rt   = (__hip_bfloat16*)xl;
  __hip_bfloat16* s0b  = (__hip_bfloat16*)td;
  float* Ptot          = (float*)t5;
  float* pg1           = (float*)td;
  float* pg4           = (float*)xxx;
  float* pg6           = (float*)x5b;

  // K0: convert + transpose all GEMM weights to bf16 [N][K]
  TrArgs ta;
  const float* srcs[8] = {Wr, Wk, Wv, Wg, Wo, w1, dw1, dw2};
  __hip_bfloat16* dsts[8] = {wrt, wkt, wvt, wgt, wot, w1t, dw1t, dw2t};
  const int Rs[8] = {HDIM, HDIM, HDIM, HDIM, HDIM, HDIM, HDIM, 64};
  const int Cs[8] = {HDIM, HDIM, HDIM, HDIM, HDIM, 160, 64, HDIM};
  for (int z = 0; z < 8; z++) { ta.src[z] = srcs[z]; ta.dst[z] = dsts[z]; ta.R[z] = Rs[z]; ta.C[z] = Cs[z]; }
  transp_kernel<<<dim3(64, 64, 8), 256, 0, stream>>>(ta);

  // K1: layernorm
  ln1_kernel<<<dim3(TLEN), 256, 0, stream>>>(x, ln1w, ln1b, xl, s1out);

  // K2: token shift -> xxx (bf16)
  tokshift_kernel<<<dim3(TLEN, HDIM / 256), 256, 0, stream>>>(xl, s1, tmx, xxx);

  // G1: t5 = tanh(xxx @ w1)  (M=1024, N=160, K=2048) -- split-K=8
  {
    GemmArgs g{};
    for (int ks = 0; ks < 8; ks++) {
      g.A[ks] = xxx + ks * 256;
      g.B[ks] = w1t + ks * 256;
      g.C[ks] = pg1 + (size_t)ks * TLEN * 160;
      g.epi[ks] = 6;
    }
    g.M = TLEN; g.N = 160; g.K = 256; g.Ks = HDIM;
    gemm_bt<<<dim3(TLEN / 128, 2, 8), 256, 0, stream>>>(g);
    comb8_tanh_f32<<<dim3(TLEN * 160 / 256), 256, 0, stream>>>(pg1, t5, TLEN * 160);
  }

  // K4: mix + x5 (5 planes, bf16)
  mix_kernel<<<dim3(HDIM / 256, TLEN / 8), 256, 0, stream>>>(t5, xl, s1, w2, tmaa, x5b);

  // G2: r, k, v, g  (batched z=4)
  {
    GemmArgs g{};
    g.A[0] = x5b + (size_t)3 * THE; g.B[0] = wrt; g.C[0] = rb; g.epi[0] = 0;
    g.A[1] = x5b + (size_t)1 * THE; g.B[1] = wkt; g.C[1] = kb; g.epi[1] = 0;
    g.A[2] = x5b + (size_t)2 * THE; g.B[2] = wvt; g.C[2] = vb; g.epi[2] = 0;
    g.A[3] = x5b + (size_t)4 * THE; g.B[3] = wgt; g.C[3] = gb; g.epi[3] = 1;
    g.M = TLEN; g.N = HDIM; g.K = HDIM; g.Ks = HDIM;
    gemm_bt<<<dim3(TLEN / 128, HDIM / 128, 4), 256, 0, stream>>>(g);
  }

  // G4: tw = tanh(mw @ dw1)  (N=64) -- split-K=8
  {
    GemmArgs g{};
    for (int ks = 0; ks < 8; ks++) {
      g.A[ks] = x5b + ks * 256;          // plane 0 = mw
      g.B[ks] = dw1t + ks * 256;
      g.C[ks] = pg4 + (size_t)ks * TLEN * 64;
      g.epi[ks] = 6;
    }
    g.M = TLEN; g.N = 64; g.K = 256; g.Ks = HDIM;
    gemm_bt<<<dim3(TLEN / 128, 1, 8), 256, 0, stream>>>(g);
    comb8_tanh_bf16<<<dim3(TLEN * 64 / 256), 256, 0, stream>>>(pg4, tw, TLEN * 64);
  }

  // G5: td = exp(-exp(clip(tw @ dw2 + p)))  (K=64)
  {
    GemmArgs g{};
    g.A[0] = tw; g.B[0] = dw2t; g.C[0] = td; g.aux[0] = dp; g.epi[0] = 4;
    g.M = TLEN; g.N = HDIM; g.K = 64; g.Ks = 64;
    gemm_bt<<<dim3(TLEN / 128, HDIM / 128, 1), 256, 0, stream>>>(g);
  }

  // Scan stage: decay factors, single local pass, chunk combine, MFMA correction
  decay_kernel<<<dim3(NC * NHEAD), 64, 0, stream>>>(rb, td, rt, Ptot);
  scan_local_kernel<<<dim3(NC * NHEAD), 256, 0, stream>>>(kb, rb, td, vb, wkv, qT);
  scan_s_kernel<<<dim3(NHEAD, HSZ), 64, 0, stream>>>(qT, Ptot, s2, s0b, s2out);
  corr_kernel<<<dim3(NC, NHEAD), 256, 0, stream>>>(rt, s0b, wkv);

  // K7: group-norm (+diag term) + gate -> yA (bf16)
  gnorm_kernel<<<dim3(TLEN, NHEAD / 4), 256, 0, stream>>>(wkv, kb, rb, tf, vb, gb, lnxw, lnxb, yA);

  // G6: out = x + yA @ W_o  -- split-K=4 (512 blocks = 2 blocks/CU: the TLP
  // threshold; r8/r10 showed 0.5/CU and 1/CU both stall at 58us)
  {
    GemmArgs g{};
    for (int ks = 0; ks < 4; ks++) {
      g.A[ks] = yA + ks * 512;
      g.B[ks] = wot + ks * 512;
      g.C[ks] = pg6 + (size_t)ks * THE;
      g.epi[ks] = 6;
    }
    g.M = TLEN; g.N = HDIM; g.K = 512; g.Ks = HDIM;
    gemm_bt<<<dim3(TLEN / 128, HDIM / 128, 4), 256, 0, stream>>>(g);
    comb4_resid<<<dim3(THE / 4 / 256), 256, 0, stream>>>(pg6, x, out0);
  }
}

// Round 12
// 269.058 us; speedup vs baseline: 1.1471x; 1.0772x over previous
//
#include <hip/hip_runtime.h>
#include <hip/hip_bf16.h>
#include <math.h>

#define TLEN 1024
#define HDIM 2048
#define NHEAD 32
#define HSZ 64
#define THE (TLEN * HDIM)
#define NC 32          // scan chunks
#define CT (TLEN / NC) // 32 timesteps per chunk

typedef __attribute__((ext_vector_type(8))) short bf16x8;
typedef __attribute__((ext_vector_type(4))) float f32x4;

__device__ __forceinline__ float waveRedSum(float v) {
#pragma unroll
  for (int off = 32; off > 0; off >>= 1) v += __shfl_xor(v, off, 64);
  return v;
}

__device__ __forceinline__ void gll16(const __hip_bfloat16* g, __hip_bfloat16* l) {
  __builtin_amdgcn_global_load_lds(
      (const __attribute__((address_space(1))) void*)g,
      (__attribute__((address_space(3))) void*)l, 16, 0, 0);
}

// ---------- weight convert + transpose: src f32 [R][C] -> dst bf16 [C][R] ----------
struct TrArgs {
  const float* src[8];
  __hip_bfloat16* dst[8];
  int R[8];
  int C[8];
};

__global__ __launch_bounds__(256) void transp_kernel(TrArgs ta) {
  const int z = blockIdx.z;
  const int R = ta.R[z], C = ta.C[z];
  const int c0 = blockIdx.x * 32, r0 = blockIdx.y * 32;
  if (c0 >= C || r0 >= R) return;
  __shared__ float tile[32][33];
  const int tx = threadIdx.x & 31, ty = threadIdx.x >> 5;
  const float* src = ta.src[z];
  __hip_bfloat16* dst = ta.dst[z];
#pragma unroll
  for (int i = 0; i < 4; i++)
    tile[ty + i * 8][tx] = src[(size_t)(r0 + ty + i * 8) * C + c0 + tx];
  __syncthreads();
#pragma unroll
  for (int i = 0; i < 4; i++)
    dst[(size_t)(c0 + ty + i * 8) * R + r0 + tx] = __float2bfloat16(tile[tx][ty + i * 8]);
}

// ---------- LayerNorm (row) + state1_out ----------
__global__ __launch_bounds__(256) void ln1_kernel(const float* __restrict__ x,
                                                  const float* __restrict__ w,
                                                  const float* __restrict__ b,
                                                  float* __restrict__ xl,
                                                  float* __restrict__ s1out) {
  const int t = blockIdx.x;
  const int tid = threadIdx.x;
  const int wid = tid >> 6, lane = tid & 63;
  const float4* xr = (const float4*)(x + (size_t)t * HDIM);
  float4 a = xr[tid];
  float4 c = xr[tid + 256];
  float va[8] = {a.x, a.y, a.z, a.w, c.x, c.y, c.z, c.w};
  float sum = 0.f;
#pragma unroll
  for (int i = 0; i < 8; i++) sum += va[i];
  sum = waveRedSum(sum);
  __shared__ float red[8];
  if (lane == 0) red[wid] = sum;
  __syncthreads();
  const float mu = (red[0] + red[1] + red[2] + red[3]) * (1.f / HDIM);
  float vs = 0.f;
#pragma unroll
  for (int i = 0; i < 8; i++) { float d = va[i] - mu; vs += d * d; }
  vs = waveRedSum(vs);
  if (lane == 0) red[4 + wid] = vs;
  __syncthreads();
  const float rstd = rsqrtf((red[4] + red[5] + red[6] + red[7]) * (1.f / HDIM) + 1e-5f);
  float* xrow = xl + (size_t)t * HDIM;
#pragma unroll
  for (int i = 0; i < 8; i++) {
    const int idx = (i < 4) ? (4 * tid + i) : (1024 + 4 * tid + (i - 4));
    const float o = (va[i] - mu) * rstd * w[idx] + b[idx];
    xrow[idx] = o;
    if (t == TLEN - 1) s1out[idx] = o;
  }
}

// ---------- token shift: xxx = xl + (past - xl) * time_maa_x ----------
__global__ __launch_bounds__(256) void tokshift_kernel(const float* __restrict__ xl,
                                                       const float* __restrict__ s1,
                                                       const float* __restrict__ tmx,
                                                       __hip_bfloat16* __restrict__ xxx) {
  const int t = blockIdx.x;
  const int h = blockIdx.y * 256 + threadIdx.x;
  const float cur = xl[(size_t)t * HDIM + h];
  const float past = (t > 0) ? xl[(size_t)(t - 1) * HDIM + h] : s1[h];
  xxx[(size_t)t * HDIM + h] = __float2bfloat16(cur + (past - cur) * tmx[h]);
}

// ---------- mix: x5[f] = xl + sx * (t5[f] @ w2[f] + time_maa[f]) ----------
__global__ __launch_bounds__(256) void mix_kernel(const float* __restrict__ t5,
                                                  const float* __restrict__ xl,
                                                  const float* __restrict__ s1,
                                                  const float* __restrict__ w2,
                                                  const float* __restrict__ maa,
                                                  __hip_bfloat16* __restrict__ x5b) {
  const int h = blockIdx.x * 256 + threadIdx.x;
  const int t0 = blockIdx.y * 8;
  __shared__ float t5L[8 * 160];
  for (int i = threadIdx.x; i < 8 * 160; i += 256) {
    const int rr = i / 160, cc = i - rr * 160;
    t5L[i] = t5[(size_t)(t0 + rr) * 160 + cc];
  }
  __syncthreads();
  float mixv[8][5];
#pragma unroll
  for (int ts = 0; ts < 8; ts++)
#pragma unroll
    for (int f = 0; f < 5; f++) mixv[ts][f] = 0.f;
#pragma unroll
  for (int f = 0; f < 5; f++) {
#pragma unroll 4
    for (int m = 0; m < 32; m++) {
      const float w2v = w2[(size_t)(f * 32 + m) * HDIM + h];
#pragma unroll
      for (int ts = 0; ts < 8; ts++) mixv[ts][f] += t5L[ts * 160 + f * 32 + m] * w2v;
    }
  }
#pragma unroll
  for (int ts = 0; ts < 8; ts++) {
    const int t = t0 + ts;
    const float cur = xl[(size_t)t * HDIM + h];
    const float past = (t > 0) ? xl[(size_t)(t - 1) * HDIM + h] : s1[h];
    const float sx = past - cur;
#pragma unroll
    for (int f = 0; f < 5; f++) {
      const float v = cur + sx * (mixv[ts][f] + maa[(size_t)f * HDIM + h]);
      x5b[(size_t)f * THE + (size_t)t * HDIM + h] = __float2bfloat16(v);
    }
  }
}

// ---------- batched MFMA GEMM: C[z] = epi( A[z](MxK) @ Bt[z](NxK)^T ) ----------
// BK=64, double-buffered LDS, counted-vmcnt pipeline (prefetch stays in flight
// across barriers), bank-conflict-free XOR swizzle. [round-8 proven structure]
// K = loop length (may be a split-K slice); Ks = row stride of A and Bt.
// epi: 0=bf16, 1=bf16 silu, 2=f32 tanh, 3=bf16 tanh, 5=f32 +residual, 6=f32 raw partial
struct GemmArgs {
  const __hip_bfloat16* A[8];
  const __hip_bfloat16* B[8];
  void* C[8];
  const float* aux[8];
  int epi[8];
  int M, N, K, Ks;
};

__global__ __launch_bounds__(256) void gemm_bt(GemmArgs ga) {
  const int z = blockIdx.z;
  const __hip_bfloat16* __restrict__ A = ga.A[z];
  const __hip_bfloat16* __restrict__ Bt = ga.B[z];
  const int N = ga.N, K = ga.K, Ks = ga.Ks;
  const int epi = ga.epi[z];
  const float* __restrict__ aux = ga.aux[z];
  void* Cz = ga.C[z];

  // [2 buffers][128 rows][64 cols] bf16 (128B rows)
  __shared__ __align__(16) __hip_bfloat16 As[2][128 * 64];
  __shared__ __align__(16) __hip_bfloat16 Bs[2][128 * 64];

  const int tid = threadIdx.x;
  const int wid = tid >> 6;
  const int lane = tid & 63;

  // XCD-aware swizzle for the 8x16 grids: cluster all 8 m-blocks of one
  // n-panel onto a single XCD so the B panel stays L2-resident.
  int bx = blockIdx.x, by = blockIdx.y;
  if (gridDim.x == 8 && gridDim.y == 16) {
    const int flat = bx + 8 * by;  // 0..127
    const int xcd = flat & 7, rem = flat >> 3;
    bx = rem & 7;
    by = xcd + 8 * (rem >> 3);
  }
  const int m0 = bx * 128;
  const int n0 = by * 128;
  const int wr = wid >> 1, wc = wid & 1;

  // Staging: call q (per wave) covers rows wid*32+q*8 .. +7.
  // lane l -> row +(l>>3), LDS slot l&7 (16B slots in a 128B row).
  // Pre-swizzled source: phys slot p of row r holds global chunk p ^ (r&7).
  const int srow = lane >> 3;              // 0..7
  const int chunkS = (lane & 7) ^ srow;    // pre-swizzled global 16B chunk
  const __hip_bfloat16* aSrcQ[4];
  const __hip_bfloat16* bSrcQ[4];
#pragma unroll
  for (int q = 0; q < 4; q++) {
    const int arow = wid * 32 + q * 8 + srow;
    int brow = n0 + arow; if (brow > N - 1) brow = N - 1;
    aSrcQ[q] = A + (size_t)(m0 + arow) * Ks + chunkS * 8;
    bSrcQ[q] = Bt + (size_t)brow * Ks + chunkS * 8;
  }

  f32x4 acc[4][4];
#pragma unroll
  for (int m = 0; m < 4; m++)
#pragma unroll
    for (int n = 0; n < 4; n++) acc[m][n] = 0.f;

  // Read side: fragment row = (wr|wc)*64 + sub*16 + lr, desired chunk
  // kg*4 + (lane>>4); phys = chunk ^ (row&7) = chunk ^ (lr&7).
  const int lr = lane & 15;
  const int cbase = lane >> 4;  // 0..3
  int aoffk[2], boffk[2];
#pragma unroll
  for (int kg = 0; kg < 2; kg++) {
    const int phys = (kg * 4 + cbase) ^ (lr & 7);
    aoffk[kg] = (wr * 64 + lr) * 64 + phys * 8;
    boffk[kg] = (wc * 64 + lr) * 64 + phys * 8;
  }

#define STAGE(BUF, KT)                                              \
  do {                                                              \
    _Pragma("unroll") for (int q = 0; q < 4; q++) {                 \
      gll16(aSrcQ[q] + (KT), &As[BUF][(wid * 32 + q * 8) * 64]);    \
      gll16(bSrcQ[q] + (KT), &Bs[BUF][(wid * 32 + q * 8) * 64]);    \
    }                                                               \
  } while (0)

  STAGE(0, 0);
  int cur = 0;
  for (int kt = 0; kt < K; kt += 64) {
    const bool more = (kt + 64 < K);
    if (more) {
      STAGE(cur ^ 1, kt + 64);                       // issue next tile early
      asm volatile("s_waitcnt vmcnt(8)" ::: "memory");  // wait PREV tile only
    } else {
      asm volatile("s_waitcnt vmcnt(0)" ::: "memory");
    }
    __builtin_amdgcn_s_barrier();
#pragma unroll
    for (int kg = 0; kg < 2; kg++) {
      bf16x8 af[4], bfv[4];
#pragma unroll
      for (int m = 0; m < 4; m++) af[m] = *(const bf16x8*)&As[cur][aoffk[kg] + m * 16 * 64];
#pragma unroll
      for (int n = 0; n < 4; n++) bfv[n] = *(const bf16x8*)&Bs[cur][boffk[kg] + n * 16 * 64];
#pragma unroll
      for (int m = 0; m < 4; m++)
#pragma unroll
        for (int n = 0; n < 4; n++)
          acc[m][n] = __builtin_amdgcn_mfma_f32_16x16x32_bf16(af[m], bfv[n], acc[m][n], 0, 0, 0);
    }
    __builtin_amdgcn_s_barrier();   // all reads done -> next STAGE may overwrite
    cur ^= 1;
  }
#undef STAGE

  const int r4 = (lane >> 4) * 4;
#pragma unroll
  for (int m = 0; m < 4; m++) {
#pragma unroll
    for (int n = 0; n < 4; n++) {
      const int gn = n0 + wc * 64 + n * 16 + lr;
      if (gn < N) {
#pragma unroll
        for (int r = 0; r < 4; r++) {
          const int gm = m0 + wr * 64 + m * 16 + r4 + r;
          const size_t idx = (size_t)gm * N + gn;
          const float v = acc[m][n][r];
          switch (epi) {
            case 0: ((__hip_bfloat16*)Cz)[idx] = __float2bfloat16(v); break;
            case 1: ((__hip_bfloat16*)Cz)[idx] = __float2bfloat16(v / (1.f + expf(-v))); break;
            case 2: ((float*)Cz)[idx] = tanhf(v); break;
            case 3: ((__hip_bfloat16*)Cz)[idx] = __float2bfloat16(tanhf(v)); break;
            case 5: ((float*)Cz)[idx] = v + aux[idx]; break;
            case 6: ((float*)Cz)[idx] = v; break;
          }
        }
      }
    }
  }
}

// ---------- split-K combines ----------
__global__ __launch_bounds__(256) void comb8_tanh_f32(const float* __restrict__ p,
                                                      float* __restrict__ o, int n) {
  const int i = blockIdx.x * 256 + threadIdx.x;
  float s = 0.f;
#pragma unroll
  for (int k = 0; k < 8; k++) s += p[(size_t)k * n + i];
  o[i] = tanhf(s);
}

__global__ __launch_bounds__(256) void comb8_tanh_bf16(const float* __restrict__ p,
                                                       __hip_bfloat16* __restrict__ o, int n) {
  const int i = blockIdx.x * 256 + threadIdx.x;
  float s = 0.f;
#pragma unroll
  for (int k = 0; k < 8; k++) s += p[(size_t)k * n + i];
  o[i] = __float2bfloat16(tanhf(s));
}

__global__ __launch_bounds__(256) void comb4_resid(const float* __restrict__ p,
                                                   const float* __restrict__ x,
                                                   float* __restrict__ o) {
  const int i = blockIdx.x * 256 + threadIdx.x;
  const float4 a = ((const float4*)p)[i];
  const float4 b = ((const float4*)(p + THE))[i];
  const float4 c = ((const float4*)(p + 2 * (size_t)THE))[i];
  const float4 d = ((const float4*)(p + 3 * (size_t)THE))[i];
  const float4 e = ((const float4*)x)[i];
  ((float4*)o)[i] = make_float4(a.x + b.x + c.x + d.x + e.x,
                                a.y + b.y + c.y + d.y + e.y,
                                a.z + b.z + c.z + d.z + e.z,
                                a.w + b.w + c.w + d.w + e.w);
}

// ---------- td = exp(-exp(clip(tw @ dw2 + dp)))  -- K=64 dot, memory-bound ----------
// Replaces the G5 GEMM dispatch (which ran 1 K-step on 128 blocks, latency-bound).
// Block: 4 t-rows x 256 n. tw rows staged f32 in LDS (broadcast reads);
// each thread reads its 128B dw2t row (dw2t = 256KB, L2-resident).
__global__ __launch_bounds__(256) void tdcalc_kernel(const __hip_bfloat16* __restrict__ tw,
                                                     const __hip_bfloat16* __restrict__ dw2t,
                                                     const float* __restrict__ dp,
                                                     float* __restrict__ td) {
  const int t0 = blockIdx.x * 4;
  const int n = blockIdx.y * 256 + threadIdx.x;
  __shared__ float twL[4][64];
  {
    const int row = threadIdx.x >> 6, col = threadIdx.x & 63;
    twL[row][col] = __bfloat162float(tw[(size_t)(t0 + row) * 64 + col]);
  }
  __syncthreads();
  float acc[4] = {0.f, 0.f, 0.f, 0.f};
  const bf16x8* drow = (const bf16x8*)(dw2t + (size_t)n * 64);
#pragma unroll
  for (int ch = 0; ch < 8; ch++) {
    const bf16x8 v = drow[ch];
#pragma unroll
    for (int e = 0; e < 8; e++) {
      const float b = __builtin_bit_cast(float,
          (unsigned)((unsigned short)v[e]) << 16);
      const int col = ch * 8 + e;
#pragma unroll
      for (int r = 0; r < 4; r++) acc[r] = fmaf(twL[r][col], b, acc[r]);
    }
  }
  const float dpn = dp[n];
#pragma unroll
  for (int r = 0; r < 4; r++) {
    float wv = acc[r] + dpn;
    wv = fminf(fmaxf(wv, -9.72f), 2.27f);
    td[(size_t)(t0 + r) * HDIM + n] = expf(-expf(wv));
  }
}

// ---------- decay: rt[c][h][t][j] = r * cumA(t-1)  (bf16) ; Ptot[c][h][j] ----------
__global__ __launch_bounds__(64) void decay_kernel(const __hip_bfloat16* __restrict__ rb,
                                                   const float* __restrict__ td,
                                                   __hip_bfloat16* __restrict__ rt,
                                                   float* __restrict__ Ptot) {
  const int blk = blockIdx.x;  // c*NHEAD + h
  const int c = blk >> 5, h = blk & 31;
  const int j = threadIdx.x;
  const int hb = h * HSZ;
  const int t0 = c * CT;
  float A = 1.f;
  for (int t = 0; t < CT; t++) {
    const size_t rowb = (size_t)(t0 + t) * HDIM + hb;
    rt[(((size_t)c * NHEAD + h) * CT + t) * HSZ + j] =
        __float2bfloat16(__bfloat162float(rb[rowb + j]) * A);
    A *= td[rowb + j];
  }
  Ptot[((size_t)c * NHEAD + h) * HSZ + j] = A;
}

// ---------- single local scan pass: zero-init per chunk; 4-way j-split ----------
__global__ __launch_bounds__(256) void scan_local_kernel(const __hip_bfloat16* __restrict__ kb,
                                                         const __hip_bfloat16* __restrict__ rb,
                                                         const float* __restrict__ td,
                                                         const __hip_bfloat16* __restrict__ vb,
                                                         float* __restrict__ wkv,
                                                         float* __restrict__ qT) {
  const int blk = blockIdx.x;           // c*NHEAD + h
  const int c = blk >> 5, h = blk & 31;
  const int w = threadIdx.x >> 6;       // j-quarter 0..3
  const int i = threadIdx.x & 63;       // lane = output row
  __shared__ float plds[2][4][64];

  float s[16];
#pragma unroll
  for (int q = 0; q < 16; q++) s[q] = 0.f;

  const int t0 = c * CT;
  const int hb = h * HSZ;

  for (int t = 0; t < CT; t++) {
    const size_t rowb = (size_t)(t0 + t) * HDIM + hb;
    const unsigned* kw = (const unsigned*)(kb + rowb + w * 16);  // 8 dwords (uniform)
    const unsigned* rw = (const unsigned*)(rb + rowb + w * 16);
    const float* tdw = td + rowb + w * 16;
    const float vi = __bfloat162float(vb[rowb + i]);
    float p = 0.f;
#pragma unroll
    for (int m = 0; m < 8; m++) {
      const unsigned kpair = kw[m];
      const unsigned rpair = rw[m];
      const float k0 = __builtin_bit_cast(float, kpair << 16);
      const float k1 = __builtin_bit_cast(float, kpair & 0xffff0000u);
      const float r0 = __builtin_bit_cast(float, rpair << 16);
      const float r1 = __builtin_bit_cast(float, rpair & 0xffff0000u);
      const float td0 = tdw[2 * m];
      const float td1 = tdw[2 * m + 1];
      const float kv0 = vi * k0;
      const float kv1 = vi * k1;
      p = fmaf(r0, s[2 * m], p);
      p = fmaf(r1, s[2 * m + 1], p);
      s[2 * m] = fmaf(s[2 * m], td0, kv0);
      s[2 * m + 1] = fmaf(s[2 * m + 1], td1, kv1);
    }
    plds[t & 1][w][i] = p;
    __syncthreads();
    if (w == 0) {
      wkv[rowb + i] = plds[t & 1][0][i] + plds[t & 1][1][i] +
                      plds[t & 1][2][i] + plds[t & 1][3][i];
    }
  }
  float* qbase = qT + (((size_t)c * NHEAD + h) * HSZ + w * 16) * HSZ + i;
#pragma unroll
  for (int q = 0; q < 16; q++) qbase[(size_t)q * HSZ] = s[q];
}

// ---------- sequential chunk combine: s0b (bf16) per chunk + s2out ----------
__global__ __launch_bounds__(64) void scan_s_kernel(const float* __restrict__ qT,
                                                    const float* __restrict__ Ptot,
                                                    const float* __restrict__ s2in,
                                                    __hip_bfloat16* __restrict__ s0b,
                                                    float* __restrict__ s2out) {
  const int h = blockIdx.x, i = blockIdx.y, j = threadIdx.x;
  float s = s2in[((size_t)h * HSZ + i) * HSZ + j];
#pragma unroll 4
  for (int c = 0; c < NC; c++) {
    s0b[(((size_t)c * NHEAD + h) * HSZ + i) * HSZ + j] = __float2bfloat16(s);
    s = fmaf(s, Ptot[((size_t)c * NHEAD + h) * HSZ + j],
             qT[(((size_t)c * NHEAD + h) * HSZ + j) * HSZ + i]);
  }
  s2out[((size_t)h * HSZ + i) * HSZ + j] = s;
}

// ---------- correction GEMM: wkv[c*CT+t][h][i] += sum_j rt[t][j] * s0b[i][j] ----------
__global__ __launch_bounds__(256) void corr_kernel(const __hip_bfloat16* __restrict__ rt,
                                                   const __hip_bfloat16* __restrict__ s0b,
                                                   float* __restrict__ wkv) {
  const int c = blockIdx.x, h = blockIdx.y;
  const int w = threadIdx.x >> 6;   // n-tile (i)
  const int lane = threadIdx.x & 63;
  const int lr = lane & 15, lk = (lane >> 4) * 8;
  const __hip_bfloat16* rbase = rt + (((size_t)c * NHEAD + h) * CT) * HSZ;
  const __hip_bfloat16* sbase = s0b + (((size_t)c * NHEAD + h) * HSZ) * HSZ;
  float* wbase = wkv + (size_t)(c * CT) * HDIM + h * HSZ;
#pragma unroll
  for (int mt = 0; mt < CT / 16; mt++) {
    f32x4 acc = {0.f, 0.f, 0.f, 0.f};
#pragma unroll
    for (int ks = 0; ks < 2; ks++) {
      bf16x8 af = *(const bf16x8*)(rbase + (size_t)(mt * 16 + lr) * HSZ + ks * 32 + lk);
      bf16x8 bf = *(const bf16x8*)(sbase + (size_t)(w * 16 + lr) * HSZ + ks * 32 + lk);
      acc = __builtin_amdgcn_mfma_f32_16x16x32_bf16(af, bf, acc, 0, 0, 0);
    }
    const int row = mt * 16 + (lane >> 4) * 4;
    const int col = w * 16 + lr;
#pragma unroll
    for (int r = 0; r < 4; r++)
      wbase[(size_t)(row + r) * HDIM + col] += acc[r];
  }
}

// ---------- group norm over HS (+diag wkv term) + scale/bias + gate ----------
__global__ __launch_bounds__(256) void gnorm_kernel(const float* __restrict__ wkv,
                                                    const __hip_bfloat16* __restrict__ kb,
                                                    const __hip_bfloat16* __restrict__ rb,
                                                    const float* __restrict__ tf,
                                                    const __hip_bfloat16* __restrict__ vb,
                                                    const __hip_bfloat16* __restrict__ gb,
                                                    const float* __restrict__ lnw,
                                                    const float* __restrict__ lnb,
                                                    __hip_bfloat16* __restrict__ yA) {
  const int t = blockIdx.x;
  const int wid = threadIdx.x >> 6, j = threadIdx.x & 63;
  const int h = blockIdx.y * 4 + wid;
  const size_t idx = (size_t)t * HDIM + h * HSZ + j;
  const float kj = __bfloat162float(kb[idx]);
  const float rj = __bfloat162float(rb[idx]);
  const float dg = waveRedSum(rj * tf[h * HSZ + j] * kj);
  const float v = wkv[idx] + dg * __bfloat162float(vb[idx]);
  const float mu = waveRedSum(v) * (1.f / HSZ);
  const float d = v - mu;
  const float var = waveRedSum(d * d) * (1.f / HSZ);
  float y = d * rsqrtf(var + 1e-5f);
  y = y * lnw[h * HSZ + j] + lnb[h * HSZ + j];
  y *= __bfloat162float(gb[idx]);
  yA[idx] = __float2bfloat16(y);
}

extern "C" void kernel_launch(void* const* d_in, const int* in_sizes, int n_in,
                              void* d_out, int out_size, void* d_ws, size_t ws_size,
                              hipStream_t stream) {
  (void)in_sizes; (void)n_in; (void)out_size; (void)ws_size;

  const float* x    = (const float*)d_in[0];
  const float* s1   = (const float*)d_in[1];
  const float* s2   = (const float*)d_in[2];
  const float* ln1w = (const float*)d_in[3];
  const float* ln1b = (const float*)d_in[4];
  const float* tmx  = (const float*)d_in[5];
  const float* tmaa = (const float*)d_in[6];
  const float* w1   = (const float*)d_in[7];
  const float* w2   = (const float*)d_in[8];
  const float* dw1  = (const float*)d_in[9];
  const float* dw2  = (const float*)d_in[10];
  const float* dp   = (const float*)d_in[11];
  const float* tf   = (const float*)d_in[12];
  const float* Wr   = (const float*)d_in[13];
  const float* Wk   = (const float*)d_in[14];
  const float* Wv   = (const float*)d_in[15];
  const float* Wg   = (const float*)d_in[16];
  const float* Wo   = (const float*)d_in[17];
  const float* lnxw = (const float*)d_in[18];
  const float* lnxb = (const float*)d_in[19];

  float* out0  = (float*)d_out;
  float* s1out = out0 + (size_t)TLEN * HDIM;
  float* s2out = s1out + HDIM;

  char* wp = (char*)d_ws;
  size_t off = 0;
  auto carve = [&](size_t bytes) -> void* {
    void* r = wp + off;
    off += (bytes + 255) & ~(size_t)255;
    return r;
  };

  __hip_bfloat16* wrt  = (__hip_bfloat16*)carve((size_t)HDIM * HDIM * 2);
  __hip_bfloat16* wkt  = (__hip_bfloat16*)carve((size_t)HDIM * HDIM * 2);
  __hip_bfloat16* wvt  = (__hip_bfloat16*)carve((size_t)HDIM * HDIM * 2);
  __hip_bfloat16* wgt  = (__hip_bfloat16*)carve((size_t)HDIM * HDIM * 2);
  __hip_bfloat16* wot  = (__hip_bfloat16*)carve((size_t)HDIM * HDIM * 2);
  __hip_bfloat16* w1t  = (__hip_bfloat16*)carve((size_t)160 * HDIM * 2);
  __hip_bfloat16* dw1t = (__hip_bfloat16*)carve((size_t)64 * HDIM * 2);
  __hip_bfloat16* dw2t = (__hip_bfloat16*)carve((size_t)HDIM * 64 * 2);
  float* xl            = (float*)carve((size_t)THE * 4);
  __hip_bfloat16* xxx  = (__hip_bfloat16*)carve((size_t)THE * 2);
  float* t5            = (float*)carve((size_t)TLEN * 160 * 4);
  __hip_bfloat16* x5b  = (__hip_bfloat16*)carve((size_t)5 * THE * 2);
  __hip_bfloat16* rb   = (__hip_bfloat16*)carve((size_t)THE * 2);
  __hip_bfloat16* kb   = (__hip_bfloat16*)carve((size_t)THE * 2);
  __hip_bfloat16* vb   = (__hip_bfloat16*)carve((size_t)THE * 2);
  __hip_bfloat16* gb   = (__hip_bfloat16*)carve((size_t)THE * 2);
  __hip_bfloat16* tw   = (__hip_bfloat16*)carve((size_t)TLEN * 64 * 2);
  float* td            = (float*)carve((size_t)THE * 4);
  float* wkv           = (float*)carve((size_t)THE * 4);
  __hip_bfloat16* yA   = (__hip_bfloat16*)carve((size_t)THE * 2);

  // Aliased scratch (all regions dead at time of use):
  //   qT   (16MB) <- x5b       (dead after G4; used in scan stage)
  //   rt   ( 4MB) <- xl        (dead after mix)
  //   s0b  ( 8MB) <- td        (dead after scan_local)
  //   Ptot (256KB)<- t5        (dead after mix)
  //   pg1  (5.2MB)<- td region (free until tdcalc writes td)
  //   pg4  ( 2MB) <- xxx       (dead after G1)
  //   pg6  (32MB) <- x5b+rb+kb+vb (contiguous carves; all dead after gnorm)
  float* qT            = (float*)x5b;
  __hip_bfloat16* rt   = (__hip_bfloat16*)xl;
  __hip_bfloat16* s0b  = (__hip_bfloat16*)td;
  float* Ptot          = (float*)t5;
  float* pg1           = (float*)td;
  float* pg4           = (float*)xxx;
  float* pg6           = (float*)x5b;

  // K0: convert + transpose all GEMM weights to bf16 [N][K]
  TrArgs ta;
  const float* srcs[8] = {Wr, Wk, Wv, Wg, Wo, w1, dw1, dw2};
  __hip_bfloat16* dsts[8] = {wrt, wkt, wvt, wgt, wot, w1t, dw1t, dw2t};
  const int Rs[8] = {HDIM, HDIM, HDIM, HDIM, HDIM, HDIM, HDIM, 64};
  const int Cs[8] = {HDIM, HDIM, HDIM, HDIM, HDIM, 160, 64, HDIM};
  for (int z = 0; z < 8; z++) { ta.src[z] = srcs[z]; ta.dst[z] = dsts[z]; ta.R[z] = Rs[z]; ta.C[z] = Cs[z]; }
  transp_kernel<<<dim3(64, 64, 8), 256, 0, stream>>>(ta);

  // K1: layernorm
  ln1_kernel<<<dim3(TLEN), 256, 0, stream>>>(x, ln1w, ln1b, xl, s1out);

  // K2: token shift -> xxx (bf16)
  tokshift_kernel<<<dim3(TLEN, HDIM / 256), 256, 0, stream>>>(xl, s1, tmx, xxx);

  // G1: t5 = tanh(xxx @ w1)  (M=1024, N=160, K=2048) -- split-K=8
  {
    GemmArgs g{};
    for (int ks = 0; ks < 8; ks++) {
      g.A[ks] = xxx + ks * 256;
      g.B[ks] = w1t + ks * 256;
      g.C[ks] = pg1 + (size_t)ks * TLEN * 160;
      g.epi[ks] = 6;
    }
    g.M = TLEN; g.N = 160; g.K = 256; g.Ks = HDIM;
    gemm_bt<<<dim3(TLEN / 128, 2, 8), 256, 0, stream>>>(g);
    comb8_tanh_f32<<<dim3(TLEN * 160 / 256), 256, 0, stream>>>(pg1, t5, TLEN * 160);
  }

  // K4: mix + x5 (5 planes, bf16)
  mix_kernel<<<dim3(HDIM / 256, TLEN / 8), 256, 0, stream>>>(t5, xl, s1, w2, tmaa, x5b);

  // G2: r, k, v, g  (batched z=4)
  {
    GemmArgs g{};
    g.A[0] = x5b + (size_t)3 * THE; g.B[0] = wrt; g.C[0] = rb; g.epi[0] = 0;
    g.A[1] = x5b + (size_t)1 * THE; g.B[1] = wkt; g.C[1] = kb; g.epi[1] = 0;
    g.A[2] = x5b + (size_t)2 * THE; g.B[2] = wvt; g.C[2] = vb; g.epi[2] = 0;
    g.A[3] = x5b + (size_t)4 * THE; g.B[3] = wgt; g.C[3] = gb; g.epi[3] = 1;
    g.M = TLEN; g.N = HDIM; g.K = HDIM; g.Ks = HDIM;
    gemm_bt<<<dim3(TLEN / 128, HDIM / 128, 4), 256, 0, stream>>>(g);
  }

  // G4: tw = tanh(mw @ dw1)  (N=64) -- split-K=8
  {
    GemmArgs g{};
    for (int ks = 0; ks < 8; ks++) {
      g.A[ks] = x5b + ks * 256;          // plane 0 = mw
      g.B[ks] = dw1t + ks * 256;
      g.C[ks] = pg4 + (size_t)ks * TLEN * 64;
      g.epi[ks] = 6;
    }
    g.M = TLEN; g.N = 64; g.K = 256; g.Ks = HDIM;
    gemm_bt<<<dim3(TLEN / 128, 1, 8), 256, 0, stream>>>(g);
    comb8_tanh_bf16<<<dim3(TLEN * 64 / 256), 256, 0, stream>>>(pg4, tw, TLEN * 64);
  }

  // G5': td = exp(-exp(clip(tw @ dw2 + p))) -- dedicated memory-bound kernel
  tdcalc_kernel<<<dim3(TLEN / 4, HDIM / 256), 256, 0, stream>>>(tw, dw2t, dp, td);

  // Scan stage: decay factors, single local pass, chunk combine, MFMA correction
  decay_kernel<<<dim3(NC * NHEAD), 64, 0, stream>>>(rb, td, rt, Ptot);
  scan_local_kernel<<<dim3(NC * NHEAD), 256, 0, stream>>>(kb, rb, td, vb, wkv, qT);
  scan_s_kernel<<<dim3(NHEAD, HSZ), 64, 0, stream>>>(qT, Ptot, s2, s0b, s2out);
  corr_kernel<<<dim3(NC, NHEAD), 256, 0, stream>>>(rt, s0b, wkv);

  // K7: group-norm (+diag term) + gate -> yA (bf16)
  gnorm_kernel<<<dim3(TLEN, NHEAD / 4), 256, 0, stream>>>(wkv, kb, rb, tf, vb, gb, lnxw, lnxb, yA);

  // G6: out = x + yA @ W_o  -- split-K=4 (512 blocks = 2 blocks/CU TLP threshold)
  {
    GemmArgs g{};
    for (int ks = 0; ks < 4; ks++) {
      g.A[ks] = yA + ks * 512;
      g.B[ks] = wot + ks * 512;
      g.C[ks] = pg6 + (size_t)ks * THE;
      g.epi[ks] = 6;
    }
    g.M = TLEN; g.N = HDIM; g.K = 512; g.Ks = HDIM;
    gemm_bt<<<dim3(TLEN / 128, HDIM / 128, 4), 256, 0, stream>>>(g);
    comb4_resid<<<dim3(THE / 4 / 256), 256, 0, stream>>>(pg6, x, out0);
  }
}